// Round 6
// baseline (494.609 us; speedup 1.0000x reference)
//
#include <hip/hip_runtime.h>
#include <math.h>

#define OBS 114
#define ROWS_PER_BLOCK 16   // 1 wave, 4 x 16-lane groups, 4 rows each
#define BSTRIDE 104         // fp32 activation buffer row stride (100 + pad)
#define XSTRIDE 118         // obs-row LDS stride: even (8B-aligned rows) and
                            // 4*118 mod 32 = 24 -> groups hit banks {0,24,16,8}: conflict-free

__device__ __forceinline__ float fast_tanh(float x) {
    float e = __expf(2.0f * x);
    return 1.0f - 2.0f * __builtin_amdgcn_rcpf(e + 1.0f);
}

template<int CTRL>
__device__ __forceinline__ float dpp_add(float x) {
    int y = __builtin_amdgcn_update_dpp(0, __float_as_int(x), CTRL, 0xF, 0xF, true);
    return x + __int_as_float(y);
}
// sum across each 16-lane row (serves 4 groups per wave simultaneously)
__device__ __forceinline__ float row16_sum(float x) {
    x = dpp_add<0xB1>(x);    // quad_perm xor1
    x = dpp_add<0x4E>(x);    // quad_perm xor2
    x = dpp_add<0x124>(x);   // row_ror:4
    x = dpp_add<0x128>(x);   // row_ror:8
    return x;
}
__device__ __forceinline__ float f4c(const float4& v, int j) {
    return j==0?v.x: j==1?v.y: j==2?v.z: v.w;
}

// ---- repack [K x 100] row-major weights into [K][16 j][8 i] so each lane's
// 7 h-slots (h = j+16i) are 2 contiguous float4 loads; masked slots -> 0 ----
__global__ __launch_bounds__(256) void repack_kernel(
    const float* __restrict__ Ac, const float* __restrict__ Lc,
    const float* __restrict__ fcW, const float* __restrict__ f1W,
    const float* __restrict__ f2W, float* __restrict__ ws)
{
    int tid = blockIdx.x*256 + threadIdx.x;   // 800 krows * 128
    if (tid >= 800*128) return;
    int krow = tid >> 7;
    int idx  = tid & 127;
    int j = idx >> 3, i = idx & 7;
    int h = j + 16*i;
    const float* src; int k;
    if (krow < 100)      { src = Ac;  k = krow; }
    else if (krow < 200) { src = Lc;  k = krow-100; }
    else if (krow < 300) { src = fcW; k = krow-200; }
    else if (krow < 700) { src = f1W; k = krow-300; }
    else                 { src = f2W; k = krow-700; }
    float v = (i < 7 && h < 100) ? src[k*100 + h] : 0.f;
    ws[tid] = v;
}

// acc[i][b] += sum_k sbuf[R0+b][k] * Wp[k][j][i]  (accumulating; zero acc outside)
// 4 rows per 16-lane group: weight loads amortized x4, 28 independent FMA chains.
// unroll 4: 16 weight dwordx4 in flight per wait -> L2 latency covered.
template<int NK4>
__device__ __forceinline__ void mm16(const float* __restrict__ Wp,
    const float (*sbuf)[BSTRIDE], int R0, int j, float acc[7][4])
{
    const float* wp = Wp + j*8;
#pragma unroll 4
    for (int k4 = 0; k4 < NK4; ++k4) {
        float4 x0 = *(const float4*)&sbuf[R0+0][k4*4];
        float4 x1 = *(const float4*)&sbuf[R0+1][k4*4];
        float4 x2 = *(const float4*)&sbuf[R0+2][k4*4];
        float4 x3 = *(const float4*)&sbuf[R0+3][k4*4];
#pragma unroll
        for (int jj=0;jj<4;++jj) {
            const float* w8 = wp + (size_t)(k4*4+jj)*128;
            float4 wlo = *(const float4*)w8;
            float4 whi = *(const float4*)(w8+4);
            float w[7] = {wlo.x,wlo.y,wlo.z,wlo.w,whi.x,whi.y,whi.z};
            float xk0 = f4c(x0,jj), xk1 = f4c(x1,jj), xk2 = f4c(x2,jj), xk3 = f4c(x3,jj);
#pragma unroll
            for (int i=0;i<7;++i) {
                acc[i][0] = fmaf(xk0, w[i], acc[i][0]);
                acc[i][1] = fmaf(xk1, w[i], acc[i][1]);
                acc[i][2] = fmaf(xk2, w[i], acc[i][2]);
                acc[i][3] = fmaf(xk3, w[i], acc[i][3]);
            }
        }
    }
}

// attention stream, 16-lane layout, 4 rows per group (rows R0+b, b=0..3).
// x comes from the LDS-staged obs rows (xbuf) -> low-latency broadcast reads.
// Pre-masked params: masked slots have w=bias=g=0 -> t=tanh(0)=0 contributes nothing.
// Writes result segment into sbuf[R0+b][h].
template<int K, int NA>
__device__ __forceinline__ void attn16(
    const float* __restrict__ W, const float* __restrict__ bb,
    const float* __restrict__ gp, const float* __restrict__ bep,
    const float (*xbuf)[XSTRIDE], int xoff,
    float (*sbuf)[BSTRIDE],
    int R0,
    const float qacc[7][4],
    const int hc[7], const float msk[7])
{
    float w[K][7], bias[7], g[7], be[7];
#pragma unroll
    for (int i=0;i<7;++i) {
#pragma unroll
        for (int k=0;k<K;++k) w[k][i] = W[k*100 + hc[i]] * msk[i];
        bias[i] = bb[hc[i]] * msk[i];
        g[i]    = gp[hc[i]] * msk[i];
        be[i]   = bep[hc[i]];
    }
    float qg[4][7], C1[4];
#pragma unroll
    for (int b=0;b<4;++b) {
        float c = 0.f;
#pragma unroll
        for (int i=0;i<7;++i) { qg[b][i] = qacc[i][b]*g[i]; c += qg[b][i]; }
        C1[b] = row16_sum(c);
    }

    float s[4], bacc[4], A[4][7];
#pragma unroll
    for (int b=0;b<4;++b) {
        s[b]=0.f; bacc[b]=0.f;
#pragma unroll
        for (int i=0;i<7;++i) A[b][i]=0.f;
    }

#pragma unroll 2
    for (int n=0;n<NA;++n) {
        float x[4][K];
#pragma unroll
        for (int b=0;b<4;++b)
#pragma unroll
            for (int k=0;k<K;++k) x[b][k] = xbuf[R0+b][xoff + n*K + k];
        float t[4][7], sa[4], sq[4], sd[4];
#pragma unroll
        for (int b=0;b<4;++b) { sa[b]=0.f; sq[b]=0.f; sd[b]=0.f; }
#pragma unroll
        for (int i=0;i<7;++i) {
#pragma unroll
            for (int b=0;b<4;++b) {
                float a = bias[i];
#pragma unroll
                for (int k=0;k<K;++k) a = fmaf(x[b][k], w[k][i], a);
                float tt = fast_tanh(a);
                t[b][i] = tt;
                sa[b] += tt;
                sq[b] = fmaf(tt,tt,sq[b]);
                sd[b] = fmaf(qg[b][i],tt,sd[b]);
            }
        }
#pragma unroll
        for (int b=0;b<4;++b) { sa[b]=row16_sum(sa[b]); sq[b]=row16_sum(sq[b]); sd[b]=row16_sum(sd[b]); }
#pragma unroll
        for (int b=0;b<4;++b) {
            float mean = sa[b]*0.01f;
            float var  = fmaf(sq[b],0.01f,-mean*mean);
            float rinv = __builtin_amdgcn_rsqf(var + 1e-5f);
            float logit = (sd[b]-mean*C1[b])*rinv;   // q.be term agent-constant -> dropped
            float wgt = __expf(fminf(logit,80.f));
            s[b] += wgt;
            float wr = wgt*rinv;
            bacc[b] = fmaf(wr,mean,bacc[b]);
#pragma unroll
            for (int i=0;i<7;++i) A[b][i] = fmaf(wr,t[b][i],A[b][i]);
        }
    }
#pragma unroll
    for (int b=0;b<4;++b) {
        float inv = __builtin_amdgcn_rcpf(s[b]);
#pragma unroll
        for (int i=0;i<7;++i)
            if (msk[i]>0.f) sbuf[R0+b][hc[i]] = fmaf(g[i], (A[b][i]-bacc[b])*inv, be[i]);
    }
}

// LN(tanh(acc+bias)) for 4 rows; masked slots: acc=0 (zeroed weights), bias=0.
__device__ __forceinline__ void ln_quad(const float acc[7][4],
    const float* __restrict__ bp, const float* __restrict__ gp, const float* __restrict__ bep,
    const int hc[7], const float msk[7], float outv[4][7])
{
    float bias[7], ga[7], be[7];
#pragma unroll
    for (int i=0;i<7;++i) { bias[i]=bp[hc[i]]*msk[i]; ga[i]=gp[hc[i]]; be[i]=bep[hc[i]]; }
    float t[4][7], sa[4], sq[4];
#pragma unroll
    for (int b=0;b<4;++b) { sa[b]=0.f; sq[b]=0.f; }
#pragma unroll
    for (int i=0;i<7;++i) {
#pragma unroll
        for (int b=0;b<4;++b) {
            float tt = fast_tanh(acc[i][b] + bias[i]);
            t[b][i] = tt; sa[b] += tt*msk[i]; sq[b] = fmaf(tt*msk[i],tt,sq[b]);
        }
    }
#pragma unroll
    for (int b=0;b<4;++b) { sa[b]=row16_sum(sa[b]); sq[b]=row16_sum(sq[b]); }
#pragma unroll
    for (int b=0;b<4;++b) {
        float mean = sa[b]*0.01f;
        float var  = fmaf(sq[b],0.01f,-mean*mean);
        float rinv = __builtin_amdgcn_rsqf(var + 1e-5f);
#pragma unroll
        for (int i=0;i<7;++i) outv[b][i] = fmaf((t[b][i]-mean)*rinv, ga[i], be[i]);
    }
}

__global__ __launch_bounds__(64, 2)
void obs_encoder_kernel(const float* __restrict__ in,
    const float* __restrict__ sW, const float* __restrict__ sb, const float* __restrict__ sg, const float* __restrict__ sbe,
    const float* __restrict__ oW, const float* __restrict__ ob, const float* __restrict__ og, const float* __restrict__ obe,
    const float* __restrict__ lW, const float* __restrict__ lb, const float* __restrict__ lg, const float* __restrict__ lbe,
    const float* __restrict__ gW, const float* __restrict__ gb, const float* __restrict__ gg_, const float* __restrict__ gbe,
    const float* __restrict__ fcb, const float* __restrict__ fcg, const float* __restrict__ fcbe,
    const float* __restrict__ f1b, const float* __restrict__ f1g, const float* __restrict__ f1be,
    const float* __restrict__ f2b, const float* __restrict__ f2g, const float* __restrict__ f2be,
    const float* __restrict__ wsf,
    float* __restrict__ out, int B)
{
    const int lane = threadIdx.x;          // 0..63, one wave per block
    const int j    = lane & 15;
    const int grp  = lane >> 4;            // 0..3
    const int R0   = grp*4;                // first sbuf row of this group
    const int base = blockIdx.x*ROWS_PER_BLOCK;

    int hc[7]; float msk[7];
#pragma unroll
    for (int i=0;i<7;++i) {
        int h = j + 16*i;
        bool v = h < 100;
        hc[i] = v ? h : 99;
        msk[i] = v ? 1.f : 0.f;
    }

    // Activation buffer: emb -> gi -> va -> vl -> vg -> h1 (f1 accumulated
    // incrementally so the [16][400] concat never materializes).
    // Obs-row buffer xbuf: full 114-float rows staged ONCE with bulk float2
    // loads; attention then reads low-latency LDS broadcasts instead of
    // latency-exposed scalar global loads. Single wave -> no barriers.
    __shared__ __align__(16) float sbuf[ROWS_PER_BLOCK][BSTRIDE];
    __shared__ __align__(16) float xbuf[ROWS_PER_BLOCK][XSTRIDE];

    // ---- stage obs rows into xbuf: lane (r,q) covers float2 chunks q,q+4,... of row r ----
    {
        int r = lane >> 2;                 // 0..15
        int q = lane & 3;                  // 0..3
        const float* src = in + (size_t)min(base + r, B-1)*OBS;
#pragma unroll
        for (int t = 0; t < 15; ++t) {
            int idx = q + 4*t;             // float2 index, 57 cover 114 floats
            if (idx < 57) {
                float2 v = *(const float2*)(src + 2*idx);   // row base 8B-aligned (456B rows)
                *(float2*)&xbuf[r][2*idx] = v;              // XSTRIDE even -> 8B-aligned
            }
        }
    }

    const float* Acp = wsf;
    const float* Lcp = wsf + 12800;
    const float* fcp = wsf + 25600;
    const float* f1p = wsf + 38400;
    const float* f2p = wsf + 89600;

    // ---- self encoder -> sbuf (4 rows per group; reads global, overlaps staging) ----
    {
        float w[4][7], bias[7], g[7], be[7];
#pragma unroll
        for (int i=0;i<7;++i) {
#pragma unroll
            for (int k=0;k<4;++k) w[k][i] = sW[k*100 + hc[i]] * msk[i];
            bias[i] = sb[hc[i]] * msk[i]; g[i] = sg[hc[i]]; be[i] = sbe[hc[i]];
        }
        float x[4][4];
#pragma unroll
        for (int b=0;b<4;++b) {
            const float* xr = in + (size_t)min(base + R0 + b, B-1)*OBS;
#pragma unroll
            for (int k=0;k<4;++k) x[b][k] = xr[k];
        }
        float t[4][7], sa[4], sq[4];
#pragma unroll
        for (int b=0;b<4;++b) { sa[b]=0.f; sq[b]=0.f; }
#pragma unroll
        for (int i=0;i<7;++i) {
#pragma unroll
            for (int b=0;b<4;++b) {
                float a = bias[i];
#pragma unroll
                for (int k=0;k<4;++k) a = fmaf(x[b][k], w[k][i], a);
                float tt = fast_tanh(a);
                t[b][i] = tt; sa[b] += tt*msk[i]; sq[b] = fmaf(tt*msk[i],tt,sq[b]);
            }
        }
#pragma unroll
        for (int b=0;b<4;++b) { sa[b]=row16_sum(sa[b]); sq[b]=row16_sum(sq[b]); }
#pragma unroll
        for (int b=0;b<4;++b) {
            float mean = sa[b]*0.01f;
            float var  = fmaf(sq[b],0.01f,-mean*mean);
            float rinv = __builtin_amdgcn_rsqf(var + 1e-5f);
#pragma unroll
            for (int i=0;i<7;++i)
                if (msk[i] > 0.f) sbuf[R0+b][hc[i]] = fmaf((t[b][i]-mean)*rinv, g[i], be[i]);
        }
    }

    // ---- qa = emb@Ac, ql = emb@Lc, tg = emb@fcW (emb still in sbuf) ----
    float accA[7][4], accL[7][4], accF[7][4];
#pragma unroll
    for (int i=0;i<7;++i)
#pragma unroll
        for (int b=0;b<4;++b) { accA[i][b]=0.f; accL[i][b]=0.f; accF[i][b]=0.f; }
    mm16<25>(Acp, sbuf, R0, j, accA);
    mm16<25>(Lcp, sbuf, R0, j, accL);
    mm16<25>(fcp, sbuf, R0, j, accF);

    float f1a[7][4];
#pragma unroll
    for (int i=0;i<7;++i)
#pragma unroll
        for (int b=0;b<4;++b) f1a[i][b]=0.f;

    // ---- gi = LN(tanh(tg + fcb)) -> sbuf (overwrites emb), f1 partial k 0..99 ----
    {
        float outv[4][7];
        ln_quad(accF, fcb, fcg, fcbe, hc, msk, outv);
#pragma unroll
        for (int b=0;b<4;++b)
#pragma unroll
            for (int i=0;i<7;++i)
                if (msk[i] > 0.f) sbuf[R0+b][hc[i]] = outv[b][i];
    }
    mm16<25>(f1p, sbuf, R0, j, f1a);

    // ---- attention streams interleaved with f1 partials (ql reused for goal per ref bug) ----
    attn16<2,15>(oW, ob, og,  obe, xbuf, 52, sbuf, R0, accA, hc, msk);
    mm16<25>(f1p + 100*128, sbuf, R0, j, f1a);
    attn16<3,16>(lW, lb, lg,  lbe, xbuf, 4,  sbuf, R0, accL, hc, msk);
    mm16<25>(f1p + 200*128, sbuf, R0, j, f1a);
    attn16<2,16>(gW, gb, gg_, gbe, xbuf, 82, sbuf, R0, accL, hc, msk);
    mm16<25>(f1p + 300*128, sbuf, R0, j, f1a);

    // ---- h1 = LN(tanh(f1a + f1b)) -> sbuf ----
    {
        float outv[4][7];
        ln_quad(f1a, f1b, f1g, f1be, hc, msk, outv);
#pragma unroll
        for (int b=0;b<4;++b)
#pragma unroll
            for (int i=0;i<7;++i)
                if (msk[i] > 0.f) sbuf[R0+b][hc[i]] = outv[b][i];
    }

    // ---- f2: [100] -> [100], LN -> out ----
    {
        float acc[7][4];
#pragma unroll
        for (int i=0;i<7;++i)
#pragma unroll
            for (int b=0;b<4;++b) acc[i][b]=0.f;
        mm16<25>(f2p, sbuf, R0, j, acc);
        float outv[4][7];
        ln_quad(acc, f2b, f2g, f2be, hc, msk, outv);
#pragma unroll
        for (int b=0;b<4;++b) {
            int row = base + R0 + b;
            if (row < B) {
#pragma unroll
                for (int i=0;i<7;++i)
                    if (msk[i] > 0.f)
                        out[(size_t)row*100 + hc[i]] = outv[b][i];
            }
        }
    }
}

extern "C" void kernel_launch(void* const* d_in, const int* in_sizes, int n_in,
                              void* d_out, int out_size, void* d_ws, size_t ws_size,
                              hipStream_t stream) {
    const float* in  = (const float*)d_in[0];
    const float* sW  = (const float*)d_in[2];
    const float* sb  = (const float*)d_in[3];
    const float* sg  = (const float*)d_in[4];
    const float* sbe = (const float*)d_in[5];
    const float* oW  = (const float*)d_in[6];
    const float* ob  = (const float*)d_in[7];
    const float* og  = (const float*)d_in[8];
    const float* obe = (const float*)d_in[9];
    const float* lW  = (const float*)d_in[10];
    const float* lb  = (const float*)d_in[11];
    const float* lg  = (const float*)d_in[12];
    const float* lbe = (const float*)d_in[13];
    const float* gW  = (const float*)d_in[14];
    const float* gb  = (const float*)d_in[15];
    const float* gg  = (const float*)d_in[16];
    const float* gbe = (const float*)d_in[17];
    const float* Ac  = (const float*)d_in[18];
    const float* Lc  = (const float*)d_in[19];
    const float* fcW = (const float*)d_in[20];
    const float* fcb = (const float*)d_in[21];
    const float* fcg = (const float*)d_in[22];
    const float* fcbe= (const float*)d_in[23];
    const float* f1W = (const float*)d_in[24];
    const float* f1b = (const float*)d_in[25];
    const float* f1g = (const float*)d_in[26];
    const float* f1be= (const float*)d_in[27];
    const float* f2W = (const float*)d_in[28];
    const float* f2b = (const float*)d_in[29];
    const float* f2g = (const float*)d_in[30];
    const float* f2be= (const float*)d_in[31];
    float* out = (float*)d_out;
    float* wsf = (float*)d_ws;

    int B = in_sizes[0] / OBS;
    repack_kernel<<<(800*128 + 255)/256, 256, 0, stream>>>(Ac, Lc, fcW, f1W, f2W, wsf);
    int blocks = (B + ROWS_PER_BLOCK - 1) / ROWS_PER_BLOCK;
    obs_encoder_kernel<<<blocks, 64, 0, stream>>>(in,
        sW, sb, sg, sbe, oW, ob, og, obe, lW, lb, lg, lbe, gW, gb, gg, gbe,
        fcb, fcg, fcbe, f1b, f1g, f1be, f2b, f2g, f2be,
        wsf, out, B);
}

// Round 7
// 299.491 us; speedup vs baseline: 1.6515x; 1.6515x over previous
//
#include <hip/hip_runtime.h>
#include <math.h>

#define OBS 114
#define ROWS_PER_BLOCK 16   // 1 wave, 4 x 16-lane groups, 4 rows each
#define BSTRIDE 104         // fp32 activation buffer row stride (100 + pad)
#define XSTRIDE 118         // obs-row LDS stride: even (8B-aligned rows); group rows hit
                            // distinct banks (r*118 mod 32 covers all even residues)

__device__ __forceinline__ float fast_tanh(float x) {
    float e = __expf(2.0f * x);
    return 1.0f - 2.0f * __builtin_amdgcn_rcpf(e + 1.0f);
}

template<int CTRL>
__device__ __forceinline__ float dpp_add(float x) {
    int y = __builtin_amdgcn_update_dpp(0, __float_as_int(x), CTRL, 0xF, 0xF, true);
    return x + __int_as_float(y);
}
// sum across each 16-lane row (serves 4 groups per wave simultaneously)
__device__ __forceinline__ float row16_sum(float x) {
    x = dpp_add<0xB1>(x);    // quad_perm xor1
    x = dpp_add<0x4E>(x);    // quad_perm xor2
    x = dpp_add<0x124>(x);   // row_ror:4
    x = dpp_add<0x128>(x);   // row_ror:8
    return x;
}
__device__ __forceinline__ float f4c(const float4& v, int j) {
    return j==0?v.x: j==1?v.y: j==2?v.z: v.w;
}

// ---- repack [K x 100] row-major weights into [K][16 j][8 i] so each lane's
// 7 h-slots (h = j+16i) are 2 contiguous float4 loads; masked slots -> 0 ----
__global__ __launch_bounds__(256) void repack_kernel(
    const float* __restrict__ Ac, const float* __restrict__ Lc,
    const float* __restrict__ fcW, const float* __restrict__ f1W,
    const float* __restrict__ f2W, float* __restrict__ ws)
{
    int tid = blockIdx.x*256 + threadIdx.x;   // 800 krows * 128
    if (tid >= 800*128) return;
    int krow = tid >> 7;
    int idx  = tid & 127;
    int j = idx >> 3, i = idx & 7;
    int h = j + 16*i;
    const float* src; int k;
    if (krow < 100)      { src = Ac;  k = krow; }
    else if (krow < 200) { src = Lc;  k = krow-100; }
    else if (krow < 300) { src = fcW; k = krow-200; }
    else if (krow < 700) { src = f1W; k = krow-300; }
    else                 { src = f2W; k = krow-700; }
    float v = (i < 7 && h < 100) ? src[k*100 + h] : 0.f;
    ws[tid] = v;
}

// acc[i][b] += sum_k sbuf[R0+b][k] * Wp[k][j][i]  (accumulating; zero acc outside)
// 4 rows per 16-lane group: weight loads amortized x4, 28 independent FMA chains.
// unroll 2 EXACTLY (round-4 proven): unroll 4 spilled (round-6, 590 MB scratch).
template<int NK4>
__device__ __forceinline__ void mm16(const float* __restrict__ Wp,
    const float (*sbuf)[BSTRIDE], int R0, int j, float acc[7][4])
{
    const float* wp = Wp + j*8;
#pragma unroll 2
    for (int k4 = 0; k4 < NK4; ++k4) {
        float4 x0 = *(const float4*)&sbuf[R0+0][k4*4];
        float4 x1 = *(const float4*)&sbuf[R0+1][k4*4];
        float4 x2 = *(const float4*)&sbuf[R0+2][k4*4];
        float4 x3 = *(const float4*)&sbuf[R0+3][k4*4];
#pragma unroll
        for (int jj=0;jj<4;++jj) {
            const float* w8 = wp + (size_t)(k4*4+jj)*128;
            float4 wlo = *(const float4*)w8;
            float4 whi = *(const float4*)(w8+4);
            float w[7] = {wlo.x,wlo.y,wlo.z,wlo.w,whi.x,whi.y,whi.z};
            float xk0 = f4c(x0,jj), xk1 = f4c(x1,jj), xk2 = f4c(x2,jj), xk3 = f4c(x3,jj);
#pragma unroll
            for (int i=0;i<7;++i) {
                acc[i][0] = fmaf(xk0, w[i], acc[i][0]);
                acc[i][1] = fmaf(xk1, w[i], acc[i][1]);
                acc[i][2] = fmaf(xk2, w[i], acc[i][2]);
                acc[i][3] = fmaf(xk3, w[i], acc[i][3]);
            }
        }
    }
}

// attention stream, 16-lane layout, 4 rows per group (rows R0+b, b=0..3).
// x from LDS-staged obs rows (broadcast reads, no global latency in the loop).
// unroll 1 EXACTLY (round-4 proven): unroll 2 contributed to the round-6 spill.
// Pre-masked params: masked slots have w=bias=g=0 -> t=tanh(0)=0 contributes nothing.
template<int K, int NA>
__device__ __forceinline__ void attn16(
    const float* __restrict__ W, const float* __restrict__ bb,
    const float* __restrict__ gp, const float* __restrict__ bep,
    const float (*xbuf)[XSTRIDE], int xoff,
    float (*sbuf)[BSTRIDE],
    int R0,
    const float qacc[7][4],
    const int hc[7], const float msk[7])
{
    float w[K][7], bias[7], g[7], be[7];
#pragma unroll
    for (int i=0;i<7;++i) {
#pragma unroll
        for (int k=0;k<K;++k) w[k][i] = W[k*100 + hc[i]] * msk[i];
        bias[i] = bb[hc[i]] * msk[i];
        g[i]    = gp[hc[i]] * msk[i];
        be[i]   = bep[hc[i]];
    }
    float qg[4][7], C1[4];
#pragma unroll
    for (int b=0;b<4;++b) {
        float c = 0.f;
#pragma unroll
        for (int i=0;i<7;++i) { qg[b][i] = qacc[i][b]*g[i]; c += qg[b][i]; }
        C1[b] = row16_sum(c);
    }

    float s[4], bacc[4], A[4][7];
#pragma unroll
    for (int b=0;b<4;++b) {
        s[b]=0.f; bacc[b]=0.f;
#pragma unroll
        for (int i=0;i<7;++i) A[b][i]=0.f;
    }

#pragma unroll 1
    for (int n=0;n<NA;++n) {
        float x[4][K];
#pragma unroll
        for (int b=0;b<4;++b)
#pragma unroll
            for (int k=0;k<K;++k) x[b][k] = xbuf[R0+b][xoff + n*K + k];
        float t[4][7], sa[4], sq[4], sd[4];
#pragma unroll
        for (int b=0;b<4;++b) { sa[b]=0.f; sq[b]=0.f; sd[b]=0.f; }
#pragma unroll
        for (int i=0;i<7;++i) {
#pragma unroll
            for (int b=0;b<4;++b) {
                float a = bias[i];
#pragma unroll
                for (int k=0;k<K;++k) a = fmaf(x[b][k], w[k][i], a);
                float tt = fast_tanh(a);
                t[b][i] = tt;
                sa[b] += tt;
                sq[b] = fmaf(tt,tt,sq[b]);
                sd[b] = fmaf(qg[b][i],tt,sd[b]);
            }
        }
#pragma unroll
        for (int b=0;b<4;++b) { sa[b]=row16_sum(sa[b]); sq[b]=row16_sum(sq[b]); sd[b]=row16_sum(sd[b]); }
#pragma unroll
        for (int b=0;b<4;++b) {
            float mean = sa[b]*0.01f;
            float var  = fmaf(sq[b],0.01f,-mean*mean);
            float rinv = __builtin_amdgcn_rsqf(var + 1e-5f);
            float logit = (sd[b]-mean*C1[b])*rinv;   // q.be term agent-constant -> dropped
            float wgt = __expf(fminf(logit,80.f));
            s[b] += wgt;
            float wr = wgt*rinv;
            bacc[b] = fmaf(wr,mean,bacc[b]);
#pragma unroll
            for (int i=0;i<7;++i) A[b][i] = fmaf(wr,t[b][i],A[b][i]);
        }
    }
#pragma unroll
    for (int b=0;b<4;++b) {
        float inv = __builtin_amdgcn_rcpf(s[b]);
#pragma unroll
        for (int i=0;i<7;++i)
            if (msk[i]>0.f) sbuf[R0+b][hc[i]] = fmaf(g[i], (A[b][i]-bacc[b])*inv, be[i]);
    }
}

// LN(tanh(acc+bias)) for 4 rows; masked slots: acc=0 (zeroed weights), bias=0.
__device__ __forceinline__ void ln_quad(const float acc[7][4],
    const float* __restrict__ bp, const float* __restrict__ gp, const float* __restrict__ bep,
    const int hc[7], const float msk[7], float outv[4][7])
{
    float bias[7], ga[7], be[7];
#pragma unroll
    for (int i=0;i<7;++i) { bias[i]=bp[hc[i]]*msk[i]; ga[i]=gp[hc[i]]; be[i]=bep[hc[i]]; }
    float t[4][7], sa[4], sq[4];
#pragma unroll
    for (int b=0;b<4;++b) { sa[b]=0.f; sq[b]=0.f; }
#pragma unroll
    for (int i=0;i<7;++i) {
#pragma unroll
        for (int b=0;b<4;++b) {
            float tt = fast_tanh(acc[i][b] + bias[i]);
            t[b][i] = tt; sa[b] += tt*msk[i]; sq[b] = fmaf(tt*msk[i],tt,sq[b]);
        }
    }
#pragma unroll
    for (int b=0;b<4;++b) { sa[b]=row16_sum(sa[b]); sq[b]=row16_sum(sq[b]); }
#pragma unroll
    for (int b=0;b<4;++b) {
        float mean = sa[b]*0.01f;
        float var  = fmaf(sq[b],0.01f,-mean*mean);
        float rinv = __builtin_amdgcn_rsqf(var + 1e-5f);
#pragma unroll
        for (int i=0;i<7;++i) outv[b][i] = fmaf((t[b][i]-mean)*rinv, ga[i], be[i]);
    }
}

__global__ __launch_bounds__(64, 2)
void obs_encoder_kernel(const float* __restrict__ in,
    const float* __restrict__ sW, const float* __restrict__ sb, const float* __restrict__ sg, const float* __restrict__ sbe,
    const float* __restrict__ oW, const float* __restrict__ ob, const float* __restrict__ og, const float* __restrict__ obe,
    const float* __restrict__ lW, const float* __restrict__ lb, const float* __restrict__ lg, const float* __restrict__ lbe,
    const float* __restrict__ gW, const float* __restrict__ gb, const float* __restrict__ gg_, const float* __restrict__ gbe,
    const float* __restrict__ fcb, const float* __restrict__ fcg, const float* __restrict__ fcbe,
    const float* __restrict__ f1b, const float* __restrict__ f1g, const float* __restrict__ f1be,
    const float* __restrict__ f2b, const float* __restrict__ f2g, const float* __restrict__ f2be,
    const float* __restrict__ wsf,
    float* __restrict__ out, int B)
{
    const int lane = threadIdx.x;          // 0..63, one wave per block
    const int j    = lane & 15;
    const int grp  = lane >> 4;            // 0..3
    const int R0   = grp*4;                // first sbuf row of this group
    const int base = blockIdx.x*ROWS_PER_BLOCK;

    int hc[7]; float msk[7];
#pragma unroll
    for (int i=0;i<7;++i) {
        int h = j + 16*i;
        bool v = h < 100;
        hc[i] = v ? h : 99;
        msk[i] = v ? 1.f : 0.f;
    }

    // Activation buffer: emb -> gi -> va -> vl -> vg -> h1 (f1 accumulated
    // incrementally so the [16][400] concat never materializes).
    // xbuf: full 114-float obs rows staged ONCE via pipelined float2 loads;
    // attention reads LDS broadcasts instead of latency-exposed scalar global
    // loads. Single wave -> wave-synchronous, no barriers.
    __shared__ __align__(16) float sbuf[ROWS_PER_BLOCK][BSTRIDE];
    __shared__ __align__(16) float xbuf[ROWS_PER_BLOCK][XSTRIDE];

    // ---- stage obs rows: lane (r,q) covers float2 chunks q, q+4, ... of row r ----
    {
        int r = lane >> 2;                 // 0..15
        int q = lane & 3;                  // 0..3
        const float* src = in + (size_t)min(base + r, B-1)*OBS;
#pragma unroll
        for (int t = 0; t < 15; ++t) {
            int idx = q + 4*t;             // float2 index; 57 float2 cover 114 floats
            if (idx < 57) {
                float2 v = *(const float2*)(src + 2*idx);   // rows 456B -> 8B-aligned
                *(float2*)&xbuf[r][2*idx] = v;
            }
        }
    }

    const float* Acp = wsf;
    const float* Lcp = wsf + 12800;
    const float* fcp = wsf + 25600;
    const float* f1p = wsf + 38400;
    const float* f2p = wsf + 89600;

    // ---- self encoder -> sbuf (4 rows per group; inputs from xbuf) ----
    {
        float w[4][7], bias[7], g[7], be[7];
#pragma unroll
        for (int i=0;i<7;++i) {
#pragma unroll
            for (int k=0;k<4;++k) w[k][i] = sW[k*100 + hc[i]] * msk[i];
            bias[i] = sb[hc[i]] * msk[i]; g[i] = sg[hc[i]]; be[i] = sbe[hc[i]];
        }
        float x[4][4];
#pragma unroll
        for (int b=0;b<4;++b)
#pragma unroll
            for (int k=0;k<4;++k) x[b][k] = xbuf[R0+b][k];
        float t[4][7], sa[4], sq[4];
#pragma unroll
        for (int b=0;b<4;++b) { sa[b]=0.f; sq[b]=0.f; }
#pragma unroll
        for (int i=0;i<7;++i) {
#pragma unroll
            for (int b=0;b<4;++b) {
                float a = bias[i];
#pragma unroll
                for (int k=0;k<4;++k) a = fmaf(x[b][k], w[k][i], a);
                float tt = fast_tanh(a);
                t[b][i] = tt; sa[b] += tt*msk[i]; sq[b] = fmaf(tt*msk[i],tt,sq[b]);
            }
        }
#pragma unroll
        for (int b=0;b<4;++b) { sa[b]=row16_sum(sa[b]); sq[b]=row16_sum(sq[b]); }
#pragma unroll
        for (int b=0;b<4;++b) {
            float mean = sa[b]*0.01f;
            float var  = fmaf(sq[b],0.01f,-mean*mean);
            float rinv = __builtin_amdgcn_rsqf(var + 1e-5f);
#pragma unroll
            for (int i=0;i<7;++i)
                if (msk[i] > 0.f) sbuf[R0+b][hc[i]] = fmaf((t[b][i]-mean)*rinv, g[i], be[i]);
        }
    }

    // ---- qa = emb@Ac, ql = emb@Lc, tg = emb@fcW (emb still in sbuf) ----
    float accA[7][4], accL[7][4], accF[7][4];
#pragma unroll
    for (int i=0;i<7;++i)
#pragma unroll
        for (int b=0;b<4;++b) { accA[i][b]=0.f; accL[i][b]=0.f; accF[i][b]=0.f; }
    mm16<25>(Acp, sbuf, R0, j, accA);
    mm16<25>(Lcp, sbuf, R0, j, accL);
    mm16<25>(fcp, sbuf, R0, j, accF);

    float f1a[7][4];
#pragma unroll
    for (int i=0;i<7;++i)
#pragma unroll
        for (int b=0;b<4;++b) f1a[i][b]=0.f;

    // ---- gi = LN(tanh(tg + fcb)) -> sbuf (overwrites emb), f1 partial k 0..99 ----
    {
        float outv[4][7];
        ln_quad(accF, fcb, fcg, fcbe, hc, msk, outv);
#pragma unroll
        for (int b=0;b<4;++b)
#pragma unroll
            for (int i=0;i<7;++i)
                if (msk[i] > 0.f) sbuf[R0+b][hc[i]] = outv[b][i];
    }
    mm16<25>(f1p, sbuf, R0, j, f1a);

    // ---- attention streams interleaved with f1 partials (ql reused for goal per ref bug) ----
    attn16<2,15>(oW, ob, og,  obe, xbuf, 52, sbuf, R0, accA, hc, msk);
    mm16<25>(f1p + 100*128, sbuf, R0, j, f1a);
    attn16<3,16>(lW, lb, lg,  lbe, xbuf, 4,  sbuf, R0, accL, hc, msk);
    mm16<25>(f1p + 200*128, sbuf, R0, j, f1a);
    attn16<2,16>(gW, gb, gg_, gbe, xbuf, 82, sbuf, R0, accL, hc, msk);
    mm16<25>(f1p + 300*128, sbuf, R0, j, f1a);

    // ---- h1 = LN(tanh(f1a + f1b)) -> sbuf ----
    {
        float outv[4][7];
        ln_quad(f1a, f1b, f1g, f1be, hc, msk, outv);
#pragma unroll
        for (int b=0;b<4;++b)
#pragma unroll
            for (int i=0;i<7;++i)
                if (msk[i] > 0.f) sbuf[R0+b][hc[i]] = outv[b][i];
    }

    // ---- f2: [100] -> [100], LN -> out ----
    {
        float acc[7][4];
#pragma unroll
        for (int i=0;i<7;++i)
#pragma unroll
            for (int b=0;b<4;++b) acc[i][b]=0.f;
        mm16<25>(f2p, sbuf, R0, j, acc);
        float outv[4][7];
        ln_quad(acc, f2b, f2g, f2be, hc, msk, outv);
#pragma unroll
        for (int b=0;b<4;++b) {
            int row = base + R0 + b;
            if (row < B) {
#pragma unroll
                for (int i=0;i<7;++i)
                    if (msk[i] > 0.f)
                        out[(size_t)row*100 + hc[i]] = outv[b][i];
            }
        }
    }
}

extern "C" void kernel_launch(void* const* d_in, const int* in_sizes, int n_in,
                              void* d_out, int out_size, void* d_ws, size_t ws_size,
                              hipStream_t stream) {
    const float* in  = (const float*)d_in[0];
    const float* sW  = (const float*)d_in[2];
    const float* sb  = (const float*)d_in[3];
    const float* sg  = (const float*)d_in[4];
    const float* sbe = (const float*)d_in[5];
    const float* oW  = (const float*)d_in[6];
    const float* ob  = (const float*)d_in[7];
    const float* og  = (const float*)d_in[8];
    const float* obe = (const float*)d_in[9];
    const float* lW  = (const float*)d_in[10];
    const float* lb  = (const float*)d_in[11];
    const float* lg  = (const float*)d_in[12];
    const float* lbe = (const float*)d_in[13];
    const float* gW  = (const float*)d_in[14];
    const float* gb  = (const float*)d_in[15];
    const float* gg  = (const float*)d_in[16];
    const float* gbe = (const float*)d_in[17];
    const float* Ac  = (const float*)d_in[18];
    const float* Lc  = (const float*)d_in[19];
    const float* fcW = (const float*)d_in[20];
    const float* fcb = (const float*)d_in[21];
    const float* fcg = (const float*)d_in[22];
    const float* fcbe= (const float*)d_in[23];
    const float* f1W = (const float*)d_in[24];
    const float* f1b = (const float*)d_in[25];
    const float* f1g = (const float*)d_in[26];
    const float* f1be= (const float*)d_in[27];
    const float* f2W = (const float*)d_in[28];
    const float* f2b = (const float*)d_in[29];
    const float* f2g = (const float*)d_in[30];
    const float* f2be= (const float*)d_in[31];
    float* out = (float*)d_out;
    float* wsf = (float*)d_ws;

    int B = in_sizes[0] / OBS;
    repack_kernel<<<(800*128 + 255)/256, 256, 0, stream>>>(Ac, Lc, fcW, f1W, f2W, wsf);
    int blocks = (B + ROWS_PER_BLOCK - 1) / ROWS_PER_BLOCK;
    obs_encoder_kernel<<<blocks, 64, 0, stream>>>(in,
        sW, sb, sg, sbe, oW, ob, og, obe, lW, lb, lg, lbe, gW, gb, gg, gbe,
        fcb, fcg, fcbe, f1b, f1g, f1be, f2b, f2g, f2be,
        wsf, out, B);
}